// Round 9
// baseline (170.919 us; speedup 1.0000x reference)
//
#include <hip/hip_runtime.h>
#include <stdint.h>

// CausalDerivative: out[b,i] = sum_h W2[i,h] * relu(sum_n x[b,n]*W1[i,h,n]*M[i,n])
//   x[b,n] = (n<16) ? (inputs[b,n]>0 ? 1 : 0) : inputs[b,n]
//   M = ones, except row 63 keeps only n==63
// B=32768, N=64, H=64. Device tensors FP32 (proven r3/6/7); dual-path kept.
//
// Round 9: r8 fixed writes but stayed ~50us -> latency-bound at ~1.5 waves/SIMD
// (occ 18.5%). Make residency architectural: block = 1024 threads = 16 waves
// (guaranteed co-resident; __launch_bounds__(1024) caps regs at 128), wave =
// 32 rows x 1 node (16 MFMA, short chain), coalesced out-tile write kept.

typedef __attribute__((ext_vector_type(8))) short short8;   // 8 bf16
typedef __attribute__((ext_vector_type(4))) float floatx4;  // MFMA acc

#define NN 64
#define HH 64
#define BB 32768
#define LDSW 20   // LDS row stride in floats (80 B, 16B-aligned rows)
#define X_ELEMS (BB * NN)        // 2097152
#define W1_ELEMS (NN * HH * NN)  // 262144

__device__ __forceinline__ unsigned short f32_to_bf16_bits(float f) {
    union { float f; unsigned int i; } c; c.f = f;
    unsigned int b = c.i;
    b += 0x7fffu + ((b >> 16) & 1u);   // RNE
    return (unsigned short)(b >> 16);
}

__device__ __forceinline__ bool sniff_bf16(const void* x) {
    // bf16 N(0,1): exponent field in [118,132] ~99%; fp32 low-mantissa halves ~6%.
    const int lane = threadIdx.x & 63;
    const ushort* xw = (const ushort*)x;
    const ushort a = xw[4 * lane];
    const ushort b = xw[4 * lane + 2];
    const int ea = (a >> 7) & 0xFF, eb = (b >> 7) & 0xFF;
    const int hit = ((ea >= 118 && ea <= 132) ? 1 : 0) + ((eb >= 118 && eb <= 132) ? 1 : 0);
    const unsigned long long m1 = __ballot(hit >= 1);
    const unsigned long long m2 = __ballot(hit >= 2);
    return (__popcll(m1) + __popcll(m2)) >= 64;
}

// ---------------- prep: gate+convert x, mask+convert W1 into bf16 workspace ----
__global__ __launch_bounds__(256, 4)
void prep_kernel(const void* __restrict__ x, const void* __restrict__ w1,
                 ushort* __restrict__ xo, ushort* __restrict__ w1o)
{
    const bool is_bf16 = sniff_bf16(x);
    const long base = ((long)blockIdx.x * 256 + (long)threadIdx.x) * 8;

    if (base < X_ELEMS) {
        const bool gate = (base & 63) < 16;   // uniform per 8-elem chunk
        short8 v;
        if (is_bf16) {
            v = *(const short8*)((const ushort*)x + base);
            if (gate) {
                #pragma unroll
                for (int j = 0; j < 8; ++j) {
                    const unsigned short u = (unsigned short)v[j];
                    const bool pos = ((u & 0x8000u) == 0) && ((u & 0x7fffu) != 0);
                    v[j] = pos ? (short)0x3F80 : (short)0;
                }
            }
        } else {
            const float* p = (const float*)x + base;
            const float4 f0 = *(const float4*)(p);
            const float4 f1 = *(const float4*)(p + 4);
            const float vals[8] = {f0.x, f0.y, f0.z, f0.w, f1.x, f1.y, f1.z, f1.w};
            #pragma unroll
            for (int j = 0; j < 8; ++j) {
                if (gate) v[j] = (vals[j] > 0.f) ? (short)0x3F80 : (short)0;
                else      v[j] = (short)f32_to_bf16_bits(vals[j]);
            }
        }
        *(short8*)(xo + base) = v;
    } else {
        const long wb = base - X_ELEMS;
        if (wb < W1_ELEMS) {
            short8 v;
            if (is_bf16) {
                v = *(const short8*)((const ushort*)w1 + wb);
            } else {
                const float* p = (const float*)w1 + wb;
                const float4 f0 = *(const float4*)(p);
                const float4 f1 = *(const float4*)(p + 4);
                const float vals[8] = {f0.x, f0.y, f0.z, f0.w, f1.x, f1.y, f1.z, f1.w};
                #pragma unroll
                for (int j = 0; j < 8; ++j) v[j] = (short)f32_to_bf16_bits(vals[j]);
            }
            const int node = (int)(wb >> 12);        // 4096 elems per node
            if (node == NN - 1) {                    // hidden node: keep only n==63
                const int w63 = (int)(wb & 63);
                #pragma unroll
                for (int j = 0; j < 8; ++j)
                    if (w63 + j != NN - 1) v[j] = 0;
            }
            *(short8*)(w1o + wb) = v;
        }
    }
}

// ---------------- main: 16-wave block, wave = 32 rows x 1 node ----------------
template<bool F32>
__device__ __forceinline__ void main_body(const ushort* __restrict__ xo,
                                          const ushort* __restrict__ w1o,
                                          const void* __restrict__ w2p,
                                          void* __restrict__ outp,
                                          float* slab, float* outTile)
{
    const int tid  = threadIdx.x;
    const int wave = tid >> 6;    // 0..15 -> node within the block's 16-node group
    const int lane = tid & 63;
    const int quad = lane >> 4;   // 0..3
    const int l16  = lane & 15;   // 0..15

    // blk = ng*1024 + rbg : the 4 ng-blocks sharing a row-chunk are 1024 apart
    // (== 0 mod 8) -> same XCD L2 for the shared xo reads.
    const int blk  = blockIdx.x;
    const int ng   = blk >> 10;         // 0..3   (16-node group)
    const int rbg  = blk & 1023;        // 0..1023 (32-row chunk)
    const int b0   = rbg * 32;
    const int node = ng * 16 + wave;

    // ---- B fragments: B[k][h] = W1[node][h][k]; h = ht*16+l16, k = ks*32+quad*8+j
    short8 bfrag[2][4];
    const ushort* w1n = w1o + node * (HH * NN);
    #pragma unroll
    for (int ks = 0; ks < 2; ++ks)
        #pragma unroll
        for (int ht = 0; ht < 4; ++ht)
            bfrag[ks][ht] = *(const short8*)(w1n + (ht * 16 + l16) * NN + ks * 32 + quad * 8);

    // ---- W2: lane (quad,l16) needs W2[node][ht*16+l16]
    float w2reg[4];
    #pragma unroll
    for (int ht = 0; ht < 4; ++ht) {
        const int idx = node * HH + ht * 16 + l16;
        if (F32) {
            w2reg[ht] = ((const float*)w2p)[idx];
        } else {
            const ushort u = ((const ushort*)w2p)[idx];
            union { unsigned int i; float f; } cv; cv.i = ((unsigned int)u) << 16;
            w2reg[ht] = cv.f;
        }
    }

    // ---- A fragments (32 rows): A[m][k] = xo[b0+m][k]; m = rt*16+l16, rt<2
    short8 afrag[2][2];
    #pragma unroll
    for (int ks = 0; ks < 2; ++ks)
        #pragma unroll
        for (int rt = 0; rt < 2; ++rt)
            afrag[ks][rt] = *(const short8*)(xo + (b0 + rt * 16 + l16) * NN + ks * 32 + quad * 8);

    // ---- MFMA: Hidden tile [32 rows x 64 h]
    floatx4 acc[2][4];
    #pragma unroll
    for (int rt = 0; rt < 2; ++rt)
        #pragma unroll
        for (int ht = 0; ht < 4; ++ht)
            acc[rt][ht] = (floatx4){0.f, 0.f, 0.f, 0.f};

    #pragma unroll
    for (int ks = 0; ks < 2; ++ks)
        #pragma unroll
        for (int rt = 0; rt < 2; ++rt)
            #pragma unroll
            for (int ht = 0; ht < 4; ++ht)
                acc[rt][ht] = __builtin_amdgcn_mfma_f32_16x16x32_bf16(
                    afrag[ks][rt], bfrag[ks][ht], acc[rt][ht], 0, 0, 0);

    // ---- epilogue: relu*W2 partials -> wave-private slab transpose (no barrier:
    // wave-private region + in-order DS pipe, proven r7/r8).
    // C layout: col(h-offset)=l16, row=quad*4+r; lane holds h = ht*16+l16.
    #pragma unroll
    for (int rt = 0; rt < 2; ++rt) {
        #pragma unroll
        for (int r = 0; r < 4; ++r) {
            float s = 0.f;
            #pragma unroll
            for (int ht = 0; ht < 4; ++ht) {
                float v = acc[rt][ht][r];
                v = v > 0.f ? v : 0.f;
                s = fmaf(v, w2reg[ht], s);
            }
            slab[(rt * 16 + quad * 4 + r) * LDSW + l16] = s;
        }
    }

    // lane pairs (L, L+32) both reduce row L (same-address LDS reads broadcast)
    const int row = lane & 31;
    const float* rowp = slab + row * LDSW;
    const float4 v0 = *(const float4*)(rowp + 0);
    const float4 v1 = *(const float4*)(rowp + 4);
    const float4 v2 = *(const float4*)(rowp + 8);
    const float4 v3 = *(const float4*)(rowp + 12);
    const float tot = (((v0.x + v0.y) + (v0.z + v0.w)) + ((v1.x + v1.y) + (v1.z + v1.w)))
                    + (((v2.x + v2.y) + (v2.z + v2.w)) + ((v3.x + v3.y) + (v3.z + v3.w)));
    if (lane < 32) outTile[row * LDSW + wave] = tot;

    __syncthreads();   // all 16 out-tile columns written

    // ---- coalesced output: first 128 threads, 16B each; 4 consecutive threads
    // fully cover each 64B line of out.
    if (tid < 128) {
        const int orow = tid >> 2;    // 0..31
        const int c    = tid & 3;
        const float4 v = *(const float4*)(outTile + orow * LDSW + c * 4);
        const size_t obase = (size_t)(b0 + orow) * NN + ng * 16 + c * 4;
        if (F32) {
            *(float4*)((float*)outp + obase) = v;
        } else {
            ushort4 o;
            o.x = f32_to_bf16_bits(v.x); o.y = f32_to_bf16_bits(v.y);
            o.z = f32_to_bf16_bits(v.z); o.w = f32_to_bf16_bits(v.w);
            *(ushort4*)((ushort*)outp + obase) = o;
        }
    }
}

__global__ __launch_bounds__(1024)
void main_kernel(const void* __restrict__ xorig,
                 const ushort* __restrict__ xo, const ushort* __restrict__ w1o,
                 const void* __restrict__ w2p, void* __restrict__ outp)
{
    __shared__ float lds[17 * 32 * LDSW];   // 16 wave slabs + out-tile = 43.5 KB
    const bool is_bf16 = sniff_bf16(xorig);
    float* slab    = &lds[(threadIdx.x >> 6) * 32 * LDSW];
    float* outTile = &lds[16 * 32 * LDSW];
    if (is_bf16) main_body<false>(xo, w1o, w2p, outp, slab, outTile);
    else         main_body<true >(xo, w1o, w2p, outp, slab, outTile);
}

// ---------------- fallback: round-6 proven single kernel ----------------------
template<bool F32>
__device__ __forceinline__ void run_body_fb(const void* xp, const void* w1p,
                                            const void* w2p, void* outp,
                                            float* myLds)
{
    const int tid  = threadIdx.x;
    const int wave = tid >> 6;
    const int lane = tid & 63;
    const int quad = lane >> 4;
    const int l16  = lane & 15;
    const int blk  = blockIdx.x;
    const int ng   = blk >> 7;
    const int rbg  = blk & 127;
    const int node = ng * 4 + wave;
    const int rowbase = rbg * 256;

    short8 bfrag[2][4];
    #pragma unroll
    for (int ks = 0; ks < 2; ++ks) {
        #pragma unroll
        for (int ht = 0; ht < 4; ++ht) {
            const int h = ht * 16 + l16;
            const int k = ks * 32 + quad * 8;
            short8 v;
            if (F32) {
                const float* p = (const float*)w1p + node * (HH * NN) + h * NN + k;
                const float4 a0 = *(const float4*)(p);
                const float4 a1 = *(const float4*)(p + 4);
                const float vals[8] = {a0.x, a0.y, a0.z, a0.w, a1.x, a1.y, a1.z, a1.w};
                #pragma unroll
                for (int j = 0; j < 8; ++j) v[j] = (short)f32_to_bf16_bits(vals[j]);
            } else {
                v = *(const short8*)((const ushort*)w1p + node * (HH * NN) + h * NN + k);
            }
            if (node == NN - 1) {
                #pragma unroll
                for (int j = 0; j < 8; ++j)
                    if (k + j != NN - 1) v[j] = 0;
            }
            bfrag[ks][ht] = v;
        }
    }

    float w2reg[4];
    #pragma unroll
    for (int ht = 0; ht < 4; ++ht) {
        const int idx = node * HH + ht * 16 + l16;
        if (F32) {
            w2reg[ht] = ((const float*)w2p)[idx];
        } else {
            const ushort u = ((const ushort*)w2p)[idx];
            union { unsigned int i; float f; } cv; cv.i = ((unsigned int)u) << 16;
            w2reg[ht] = cv.f;
        }
    }

    #pragma unroll 1
    for (int it = 0; it < 4; ++it) {
        const int b0 = rowbase + it * 64;
        short8 afrag[2][4];
        #pragma unroll
        for (int ks = 0; ks < 2; ++ks) {
            #pragma unroll
            for (int rt = 0; rt < 4; ++rt) {
                const int rowg = b0 + rt * 16 + l16;
                const int k    = ks * 32 + quad * 8;
                const bool gate = (ks == 0 && quad < 2);
                short8 v;
                if (F32) {
                    const float* p = (const float*)xp + rowg * NN + k;
                    const float4 a0 = *(const float4*)(p);
                    const float4 a1 = *(const float4*)(p + 4);
                    const float vals[8] = {a0.x, a0.y, a0.z, a0.w, a1.x, a1.y, a1.z, a1.w};
                    #pragma unroll
                    for (int j = 0; j < 8; ++j) {
                        if (gate) v[j] = (vals[j] > 0.f) ? (short)0x3F80 : (short)0;
                        else      v[j] = (short)f32_to_bf16_bits(vals[j]);
                    }
                } else {
                    v = *(const short8*)((const ushort*)xp + rowg * NN + k);
                    if (gate) {
                        #pragma unroll
                        for (int j = 0; j < 8; ++j) {
                            const unsigned short u = (unsigned short)v[j];
                            const bool pos = ((u & 0x8000u) == 0) && ((u & 0x7fffu) != 0);
                            v[j] = pos ? (short)0x3F80 : (short)0;
                        }
                    }
                }
                afrag[ks][rt] = v;
            }
        }

        floatx4 acc[4][4];
        #pragma unroll
        for (int rt = 0; rt < 4; ++rt)
            #pragma unroll
            for (int ht = 0; ht < 4; ++ht)
                acc[rt][ht] = (floatx4){0.f, 0.f, 0.f, 0.f};
        #pragma unroll
        for (int ks = 0; ks < 2; ++ks)
            #pragma unroll
            for (int rt = 0; rt < 4; ++rt)
                #pragma unroll
                for (int ht = 0; ht < 4; ++ht)
                    acc[rt][ht] = __builtin_amdgcn_mfma_f32_16x16x32_bf16(
                        afrag[ks][rt], bfrag[ks][ht], acc[rt][ht], 0, 0, 0);

        #pragma unroll
        for (int rt = 0; rt < 4; ++rt) {
            #pragma unroll
            for (int r = 0; r < 4; ++r) {
                float s = 0.f;
                #pragma unroll
                for (int ht = 0; ht < 4; ++ht) {
                    float v = acc[rt][ht][r];
                    v = v > 0.f ? v : 0.f;
                    s = fmaf(v, w2reg[ht], s);
                }
                myLds[(rt * 16 + quad * 4 + r) * LDSW + l16] = s;
            }
        }
        __syncthreads();
        const float* rowp = myLds + lane * LDSW;
        const float4 v0 = *(const float4*)(rowp + 0);
        const float4 v1 = *(const float4*)(rowp + 4);
        const float4 v2 = *(const float4*)(rowp + 8);
        const float4 v3 = *(const float4*)(rowp + 12);
        const float tot = (((v0.x + v0.y) + (v0.z + v0.w)) + ((v1.x + v1.y) + (v1.z + v1.w)))
                        + (((v2.x + v2.y) + (v2.z + v2.w)) + ((v3.x + v3.y) + (v3.z + v3.w)));
        if (F32) ((float*) outp)[(size_t)(b0 + lane) * NN + node] = tot;
        else     ((ushort*)outp)[(size_t)(b0 + lane) * NN + node] = f32_to_bf16_bits(tot);
        __syncthreads();
    }
}

__global__ __launch_bounds__(256, 2)
void fallback_kernel(const void* __restrict__ x, const void* __restrict__ W1,
                     const void* __restrict__ W2, void* __restrict__ out)
{
    __shared__ float lds[4][64 * LDSW];
    const bool is_bf16 = sniff_bf16(x);
    float* myLds = &lds[threadIdx.x >> 6][0];
    if (is_bf16) run_body_fb<false>(x, W1, W2, out, myLds);
    else         run_body_fb<true >(x, W1, W2, out, myLds);
}

extern "C" void kernel_launch(void* const* d_in, const int* in_sizes, int n_in,
                              void* d_out, int out_size, void* d_ws, size_t ws_size,
                              hipStream_t stream) {
    // Resolve inputs by element count (robust to the scalar t being dropped):
    //   inputs = 2097152, W1 = 262144, W2 = first 4096 (adjacency is the other 4096).
    int i_in = -1, i_w1 = -1, i_w2 = -1;
    for (int i = 0; i < n_in; ++i) {
        const int s = in_sizes[i];
        if      (s == BB * NN  && i_in < 0) i_in = i;
        else if (s == NN*HH*NN && i_w1 < 0) i_w1 = i;
        else if (s == NN*HH    && i_w2 < 0) i_w2 = i;
    }
    if (i_in < 0) i_in = (n_in > 1) ? 1 : 0;
    if (i_w1 < 0) i_w1 = i_in + 1;
    if (i_w2 < 0) i_w2 = i_w1 + 1;

    const size_t need = (size_t)(X_ELEMS + W1_ELEMS) * sizeof(ushort);  // 4.5 MiB
    if (ws_size >= need) {
        ushort* xo  = (ushort*)d_ws;
        ushort* w1o = xo + X_ELEMS;
        prep_kernel<<<dim3((X_ELEMS + W1_ELEMS) / (256 * 8)), dim3(256), 0, stream>>>(
            d_in[i_in], d_in[i_w1], xo, w1o);
        main_kernel<<<dim3(4 * 1024), dim3(1024), 0, stream>>>(
            d_in[i_in], xo, w1o, d_in[i_w2], d_out);
    } else {
        fallback_kernel<<<dim3(16 * 128), dim3(256), 0, stream>>>(
            d_in[i_in], d_in[i_w1], d_in[i_w2], d_out);
    }
}

// Round 11
// 118.650 us; speedup vs baseline: 1.4405x; 1.4405x over previous
//
#include <hip/hip_runtime.h>
#include <stdint.h>

// CausalDerivative: out[b,i] = sum_h W2[i,h] * relu(sum_n x[b,n]*W1[i,h,n]*M[i,n])
//   x[b,n] = (n<16) ? (inputs[b,n]>0 ? 1 : 0) : inputs[b,n]
//   M = ones, except row 63 keeps only n==63
// B=32768, N=64, H=64. Device tensors FP32 (proven r3/6/7); dual-path kept.
//
// Round 11: r10 (transposed GEMM, in-lane h-reduction, conflict-free out-tile)
// with the dropped wcur<-wnxt prefetch rotation RESTORED (r10's only bug: all
// 4 node-iterations used node 0's W1 fragments).

typedef __attribute__((ext_vector_type(8))) short short8;   // 8 bf16
typedef __attribute__((ext_vector_type(4))) float floatx4;  // MFMA acc

#define NN 64
#define HH 64
#define BB 32768
#define OTW 17    // out-tile row stride in floats (odd -> conflict-free)
#define X_ELEMS (BB * NN)        // 2097152
#define W1_ELEMS (NN * HH * NN)  // 262144

__device__ __forceinline__ unsigned short f32_to_bf16_bits(float f) {
    union { float f; unsigned int i; } c; c.f = f;
    unsigned int b = c.i;
    b += 0x7fffu + ((b >> 16) & 1u);   // RNE
    return (unsigned short)(b >> 16);
}

__device__ __forceinline__ bool sniff_bf16(const void* x) {
    // bf16 N(0,1): exponent field in [118,132] ~99%; fp32 low-mantissa halves ~6%.
    const int lane = threadIdx.x & 63;
    const ushort* xw = (const ushort*)x;
    const ushort a = xw[4 * lane];
    const ushort b = xw[4 * lane + 2];
    const int ea = (a >> 7) & 0xFF, eb = (b >> 7) & 0xFF;
    const int hit = ((ea >= 118 && ea <= 132) ? 1 : 0) + ((eb >= 118 && eb <= 132) ? 1 : 0);
    const unsigned long long m1 = __ballot(hit >= 1);
    const unsigned long long m2 = __ballot(hit >= 2);
    return (__popcll(m1) + __popcll(m2)) >= 64;
}

// ---------------- prep: gate+convert x, mask+convert W1 into bf16 workspace ----
__global__ __launch_bounds__(256, 4)
void prep_kernel(const void* __restrict__ x, const void* __restrict__ w1,
                 ushort* __restrict__ xo, ushort* __restrict__ w1o)
{
    const bool is_bf16 = sniff_bf16(x);
    const long base = ((long)blockIdx.x * 256 + (long)threadIdx.x) * 8;

    if (base < X_ELEMS) {
        const bool gate = (base & 63) < 16;   // uniform per 8-elem chunk
        short8 v;
        if (is_bf16) {
            v = *(const short8*)((const ushort*)x + base);
            if (gate) {
                #pragma unroll
                for (int j = 0; j < 8; ++j) {
                    const unsigned short u = (unsigned short)v[j];
                    const bool pos = ((u & 0x8000u) == 0) && ((u & 0x7fffu) != 0);
                    v[j] = pos ? (short)0x3F80 : (short)0;
                }
            }
        } else {
            const float* p = (const float*)x + base;
            const float4 f0 = *(const float4*)(p);
            const float4 f1 = *(const float4*)(p + 4);
            const float vals[8] = {f0.x, f0.y, f0.z, f0.w, f1.x, f1.y, f1.z, f1.w};
            #pragma unroll
            for (int j = 0; j < 8; ++j) {
                if (gate) v[j] = (vals[j] > 0.f) ? (short)0x3F80 : (short)0;
                else      v[j] = (short)f32_to_bf16_bits(vals[j]);
            }
        }
        *(short8*)(xo + base) = v;
    } else {
        const long wb = base - X_ELEMS;
        if (wb < W1_ELEMS) {
            short8 v;
            if (is_bf16) {
                v = *(const short8*)((const ushort*)w1 + wb);
            } else {
                const float* p = (const float*)w1 + wb;
                const float4 f0 = *(const float4*)(p);
                const float4 f1 = *(const float4*)(p + 4);
                const float vals[8] = {f0.x, f0.y, f0.z, f0.w, f1.x, f1.y, f1.z, f1.w};
                #pragma unroll
                for (int j = 0; j < 8; ++j) v[j] = (short)f32_to_bf16_bits(vals[j]);
            }
            const int node = (int)(wb >> 12);        // 4096 elems per node
            if (node == NN - 1) {                    // hidden node: keep only n==63
                const int w63 = (int)(wb & 63);
                #pragma unroll
                for (int j = 0; j < 8; ++j)
                    if (w63 + j != NN - 1) v[j] = 0;
            }
            *(short8*)(w1o + wb) = v;
        }
    }
}

// ---------------- main: transposed MFMA, in-lane h-reduction ------------------
template<bool F32>
__device__ __forceinline__ void main_body(const ushort* __restrict__ xo,
                                          const ushort* __restrict__ w1o,
                                          const void* __restrict__ w2p,
                                          void* __restrict__ outp,
                                          float* outTile)
{
    const int tid  = threadIdx.x;
    const int wave = tid >> 6;
    const int lane = tid & 63;
    const int quad = lane >> 4;   // 0..3
    const int l16  = lane & 15;   // 0..15

    // blk = ng*512 + rbg : the 4 ng-blocks sharing an x row-chunk are 512 apart
    // (== 0 mod 8) -> same XCD L2 for the shared xo reads.
    const int blk  = blockIdx.x;
    const int ng   = blk >> 9;          // 0..3   (16-node group)
    const int rbg  = blk & 511;         // 0..511 (64-row chunk)
    const int b0   = rbg * 64;
    const int nbase = ng * 16 + wave * 4;   // this wave's 4 nodes

    // ---- x fragments, loaded ONCE (reused by 4 node-GEMMs). Role: MFMA *B*
    //      B[k][bcol] = xo[b0+bcol][k]; bcol = nt*16+l16, k = ks*32+quad*8+j
    short8 xfrag[2][4];
    #pragma unroll
    for (int ks = 0; ks < 2; ++ks)
        #pragma unroll
        for (int nt = 0; nt < 4; ++nt)
            xfrag[ks][nt] = *(const short8*)(xo + (b0 + nt * 16 + l16) * NN + ks * 32 + quad * 8);

    // ---- W1 fragments for node 0, then prefetch one node ahead. Role: MFMA *A*
    //      A[h][k] = W1[node][h][k]; h = mt*16+l16, k = ks*32+quad*8+j
    short8 wcur[2][4], wnxt[2][4];
    {
        const ushort* w1n = w1o + nbase * (HH * NN);
        #pragma unroll
        for (int ks = 0; ks < 2; ++ks)
            #pragma unroll
            for (int mt = 0; mt < 4; ++mt)
                wcur[ks][mt] = *(const short8*)(w1n + (mt * 16 + l16) * NN + ks * 32 + quad * 8);
    }

    #pragma unroll 1
    for (int nl = 0; nl < 4; ++nl) {
        const int node = nbase + nl;

        if (nl < 3) {
            const ushort* w1n = w1o + (node + 1) * (HH * NN);
            #pragma unroll
            for (int ks = 0; ks < 2; ++ks)
                #pragma unroll
                for (int mt = 0; mt < 4; ++mt)
                    wnxt[ks][mt] = *(const short8*)(w1n + (mt * 16 + l16) * NN + ks * 32 + quad * 8);
        }

        // ---- W2 for this node: lane needs W2[node][mt*16 + quad*4 + r], r=0..3
        float w2v[4][4];
        #pragma unroll
        for (int mt = 0; mt < 4; ++mt) {
            const int idx = node * HH + mt * 16 + quad * 4;
            if (F32) {
                const float4 w = *(const float4*)((const float*)w2p + idx);
                w2v[mt][0] = w.x; w2v[mt][1] = w.y; w2v[mt][2] = w.z; w2v[mt][3] = w.w;
            } else {
                const ushort4 w = *(const ushort4*)((const ushort*)w2p + idx);
                union { unsigned int i; float f; } c0, c1, c2, c3;
                c0.i = ((unsigned int)w.x) << 16; c1.i = ((unsigned int)w.y) << 16;
                c2.i = ((unsigned int)w.z) << 16; c3.i = ((unsigned int)w.w) << 16;
                w2v[mt][0] = c0.f; w2v[mt][1] = c1.f; w2v[mt][2] = c2.f; w2v[mt][3] = c3.f;
            }
        }

        // ---- MFMA (transposed): acc[mt][nt] = Hid^T tile; D row = h offset
        // (quad*4+r within mt), D col = batch (l16 within nt).
        floatx4 acc[4][4];
        #pragma unroll
        for (int mt = 0; mt < 4; ++mt)
            #pragma unroll
            for (int nt = 0; nt < 4; ++nt)
                acc[mt][nt] = (floatx4){0.f, 0.f, 0.f, 0.f};

        #pragma unroll
        for (int ks = 0; ks < 2; ++ks)
            #pragma unroll
            for (int mt = 0; mt < 4; ++mt)
                #pragma unroll
                for (int nt = 0; nt < 4; ++nt)
                    acc[mt][nt] = __builtin_amdgcn_mfma_f32_16x16x32_bf16(
                        wcur[ks][mt], xfrag[ks][nt], acc[mt][nt], 0, 0, 0);

        // ---- epilogue, all in-lane: psum[nt] = sum over this lane's 16 h-vals
        float psum[4];
        #pragma unroll
        for (int nt = 0; nt < 4; ++nt) {
            float s0 = 0.f, s1 = 0.f;
            #pragma unroll
            for (int mt = 0; mt < 4; ++mt) {
                float a0 = acc[mt][nt][0]; a0 = a0 > 0.f ? a0 : 0.f;
                float a1 = acc[mt][nt][1]; a1 = a1 > 0.f ? a1 : 0.f;
                float a2 = acc[mt][nt][2]; a2 = a2 > 0.f ? a2 : 0.f;
                float a3 = acc[mt][nt][3]; a3 = a3 > 0.f ? a3 : 0.f;
                s0 = fmaf(a0, w2v[mt][0], s0); s1 = fmaf(a1, w2v[mt][1], s1);
                s0 = fmaf(a2, w2v[mt][2], s0); s1 = fmaf(a3, w2v[mt][3], s1);
            }
            psum[nt] = s0 + s1;
        }

        // reduce across the 4 quads (same batch col, different h ranges)
        #pragma unroll
        for (int nt = 0; nt < 4; ++nt) {
            psum[nt] += __shfl_xor(psum[nt], 16, 64);
            psum[nt] += __shfl_xor(psum[nt], 32, 64);
        }

        // lane's batch row == lane  (nt = quad, col = l16): select psum[quad]
        const float val = (quad == 0) ? psum[0] : (quad == 1) ? psum[1]
                         : (quad == 2) ? psum[2] : psum[3];
        outTile[lane * OTW + wave * 4 + nl] = val;   // stride-17: conflict-free

        // rotate prefetched W1 fragments into place (r10's missing step)
        if (nl < 3) {
            #pragma unroll
            for (int ks = 0; ks < 2; ++ks)
                #pragma unroll
                for (int mt = 0; mt < 4; ++mt)
                    wcur[ks][mt] = wnxt[ks][mt];
        }
    }

    __syncthreads();   // all 16 out-tile columns written

    // ---- coalesced output: thread -> (row = tid>>2, c = tid&3), 16B each;
    // 4 consecutive threads fully cover each 64B line of out.
    const int row = tid >> 2;
    const int c   = tid & 3;
    const float* rp = outTile + row * OTW + c * 4;
    const float4 v = make_float4(rp[0], rp[1], rp[2], rp[3]);
    const size_t obase = (size_t)(b0 + row) * NN + ng * 16 + c * 4;
    if (F32) {
        *(float4*)((float*)outp + obase) = v;
    } else {
        ushort4 o;
        o.x = f32_to_bf16_bits(v.x); o.y = f32_to_bf16_bits(v.y);
        o.z = f32_to_bf16_bits(v.z); o.w = f32_to_bf16_bits(v.w);
        *(ushort4*)((ushort*)outp + obase) = o;
    }
}

__global__ __launch_bounds__(256, 2)
void main_kernel(const void* __restrict__ xorig,
                 const ushort* __restrict__ xo, const ushort* __restrict__ w1o,
                 const void* __restrict__ w2p, void* __restrict__ outp)
{
    __shared__ float outTile[64 * OTW];   // 4.35 KB
    const bool is_bf16 = sniff_bf16(xorig);
    if (is_bf16) main_body<false>(xo, w1o, w2p, outp, outTile);
    else         main_body<true >(xo, w1o, w2p, outp, outTile);
}

// ---------------- fallback: round-6 proven single kernel ----------------------
#define LDSW 20
template<bool F32>
__device__ __forceinline__ void run_body_fb(const void* xp, const void* w1p,
                                            const void* w2p, void* outp,
                                            float* myLds)
{
    const int tid  = threadIdx.x;
    const int wave = tid >> 6;
    const int lane = tid & 63;
    const int quad = lane >> 4;
    const int l16  = lane & 15;
    const int blk  = blockIdx.x;
    const int ng   = blk >> 7;
    const int rbg  = blk & 127;
    const int node = ng * 4 + wave;
    const int rowbase = rbg * 256;

    short8 bfrag[2][4];
    #pragma unroll
    for (int ks = 0; ks < 2; ++ks) {
        #pragma unroll
        for (int ht = 0; ht < 4; ++ht) {
            const int h = ht * 16 + l16;
            const int k = ks * 32 + quad * 8;
            short8 v;
            if (F32) {
                const float* p = (const float*)w1p + node * (HH * NN) + h * NN + k;
                const float4 a0 = *(const float4*)(p);
                const float4 a1 = *(const float4*)(p + 4);
                const float vals[8] = {a0.x, a0.y, a0.z, a0.w, a1.x, a1.y, a1.z, a1.w};
                #pragma unroll
                for (int j = 0; j < 8; ++j) v[j] = (short)f32_to_bf16_bits(vals[j]);
            } else {
                v = *(const short8*)((const ushort*)w1p + node * (HH * NN) + h * NN + k);
            }
            if (node == NN - 1) {
                #pragma unroll
                for (int j = 0; j < 8; ++j)
                    if (k + j != NN - 1) v[j] = 0;
            }
            bfrag[ks][ht] = v;
        }
    }

    float w2reg[4];
    #pragma unroll
    for (int ht = 0; ht < 4; ++ht) {
        const int idx = node * HH + ht * 16 + l16;
        if (F32) {
            w2reg[ht] = ((const float*)w2p)[idx];
        } else {
            const ushort u = ((const ushort*)w2p)[idx];
            union { unsigned int i; float f; } cv; cv.i = ((unsigned int)u) << 16;
            w2reg[ht] = cv.f;
        }
    }

    #pragma unroll 1
    for (int it = 0; it < 4; ++it) {
        const int b0 = rowbase + it * 64;
        short8 afrag[2][4];
        #pragma unroll
        for (int ks = 0; ks < 2; ++ks) {
            #pragma unroll
            for (int rt = 0; rt < 4; ++rt) {
                const int rowg = b0 + rt * 16 + l16;
                const int k    = ks * 32 + quad * 8;
                const bool gate = (ks == 0 && quad < 2);
                short8 v;
                if (F32) {
                    const float* p = (const float*)xp + rowg * NN + k;
                    const float4 a0 = *(const float4*)(p);
                    const float4 a1 = *(const float4*)(p + 4);
                    const float vals[8] = {a0.x, a0.y, a0.z, a0.w, a1.x, a1.y, a1.z, a1.w};
                    #pragma unroll
                    for (int j = 0; j < 8; ++j) {
                        if (gate) v[j] = (vals[j] > 0.f) ? (short)0x3F80 : (short)0;
                        else      v[j] = (short)f32_to_bf16_bits(vals[j]);
                    }
                } else {
                    v = *(const short8*)((const ushort*)xp + rowg * NN + k);
                    if (gate) {
                        #pragma unroll
                        for (int j = 0; j < 8; ++j) {
                            const unsigned short u = (unsigned short)v[j];
                            const bool pos = ((u & 0x8000u) == 0) && ((u & 0x7fffu) != 0);
                            v[j] = pos ? (short)0x3F80 : (short)0;
                        }
                    }
                }
                afrag[ks][rt] = v;
            }
        }

        floatx4 acc[4][4];
        #pragma unroll
        for (int rt = 0; rt < 4; ++rt)
            #pragma unroll
            for (int ht = 0; ht < 4; ++ht)
                acc[rt][ht] = (floatx4){0.f, 0.f, 0.f, 0.f};
        #pragma unroll
        for (int ks = 0; ks < 2; ++ks)
            #pragma unroll
            for (int rt = 0; rt < 4; ++rt)
                #pragma unroll
                for (int ht = 0; ht < 4; ++ht)
                    acc[rt][ht] = __builtin_amdgcn_mfma_f32_16x16x32_bf16(
                        afrag[ks][rt], bfrag[ks][ht], acc[rt][ht], 0, 0, 0);

        #pragma unroll
        for (int rt = 0; rt < 4; ++rt) {
            #pragma unroll
            for (int r = 0; r < 4; ++r) {
                float s = 0.f;
                #pragma unroll
                for (int ht = 0; ht < 4; ++ht) {
                    float v = acc[rt][ht][r];
                    v = v > 0.f ? v : 0.f;
                    s = fmaf(v, w2reg[ht], s);
                }
                myLds[(rt * 16 + quad * 4 + r) * LDSW + l16] = s;
            }
        }
        __syncthreads();
        const float* rowp = myLds + lane * LDSW;
        const float4 v0 = *(const float4*)(rowp + 0);
        const float4 v1 = *(const float4*)(rowp + 4);
        const float4 v2 = *(const float4*)(rowp + 8);
        const float4 v3 = *(const float4*)(rowp + 12);
        const float tot = (((v0.x + v0.y) + (v0.z + v0.w)) + ((v1.x + v1.y) + (v1.z + v1.w)))
                        + (((v2.x + v2.y) + (v2.z + v2.w)) + ((v3.x + v3.y) + (v3.z + v3.w)));
        if (F32) ((float*) outp)[(size_t)(b0 + lane) * NN + node] = tot;
        else     ((ushort*)outp)[(size_t)(b0 + lane) * NN + node] = f32_to_bf16_bits(tot);
        __syncthreads();
    }
}

__global__ __launch_bounds__(256, 2)
void fallback_kernel(const void* __restrict__ x, const void* __restrict__ W1,
                     const void* __restrict__ W2, void* __restrict__ out)
{
    __shared__ float lds[4][64 * LDSW];
    const bool is_bf16 = sniff_bf16(x);
    float* myLds = &lds[threadIdx.x >> 6][0];
    if (is_bf16) run_body_fb<false>(x, W1, W2, out, myLds);
    else         run_body_fb<true >(x, W1, W2, out, myLds);
}

extern "C" void kernel_launch(void* const* d_in, const int* in_sizes, int n_in,
                              void* d_out, int out_size, void* d_ws, size_t ws_size,
                              hipStream_t stream) {
    // Resolve inputs by element count (robust to the scalar t being dropped):
    //   inputs = 2097152, W1 = 262144, W2 = first 4096 (adjacency is the other 4096).
    int i_in = -1, i_w1 = -1, i_w2 = -1;
    for (int i = 0; i < n_in; ++i) {
        const int s = in_sizes[i];
        if      (s == BB * NN  && i_in < 0) i_in = i;
        else if (s == NN*HH*NN && i_w1 < 0) i_w1 = i;
        else if (s == NN*HH    && i_w2 < 0) i_w2 = i;
    }
    if (i_in < 0) i_in = (n_in > 1) ? 1 : 0;
    if (i_w1 < 0) i_w1 = i_in + 1;
    if (i_w2 < 0) i_w2 = i_w1 + 1;

    const size_t need = (size_t)(X_ELEMS + W1_ELEMS) * sizeof(ushort);  // 4.5 MiB
    if (ws_size >= need) {
        ushort* xo  = (ushort*)d_ws;
        ushort* w1o = xo + X_ELEMS;
        prep_kernel<<<dim3((X_ELEMS + W1_ELEMS) / (256 * 8)), dim3(256), 0, stream>>>(
            d_in[i_in], d_in[i_w1], xo, w1o);
        main_kernel<<<dim3(4 * 512), dim3(256), 0, stream>>>(
            d_in[i_in], xo, w1o, d_in[i_w2], d_out);
    } else {
        fallback_kernel<<<dim3(16 * 128), dim3(256), 0, stream>>>(
            d_in[i_in], d_in[i_w1], d_in[i_w2], d_out);
    }
}

// Round 12
// 115.115 us; speedup vs baseline: 1.4848x; 1.0307x over previous
//
#include <hip/hip_runtime.h>
#include <stdint.h>

// CausalDerivative: out[b,i] = sum_h W2[i,h] * relu(sum_n x[b,n]*W1[i,h,n]*M[i,n])
//   x[b,n] = (n<16) ? (inputs[b,n]>0 ? 1 : 0) : inputs[b,n]
//   M = ones, except row 63 keeps only n==63
// B=32768, N=64, H=64. Device tensors FP32 (proven r3/6/7); dual-path kept.
//
// Round 12: r7/r8/r11 all plateau ~50us -> latency-bound from thin waves
// (4 node-units each, ~2 waves/SIMD). Go fat: block = 64 rows x 64 nodes,
// wave = 16 nodes; x-frags loaded once reused 16x; W1 ping-pong prefetch
// (no reg-copy rotation); transposed-GEMM in-lane epilogue (proven r11);
// each thread writes one full 64B output line.

typedef __attribute__((ext_vector_type(8))) short short8;   // 8 bf16
typedef __attribute__((ext_vector_type(4))) float floatx4;  // MFMA acc

#define NN 64
#define HH 64
#define BB 32768
#define OTW 65    // out-tile row stride in floats (odd -> conflict-benign)
#define X_ELEMS (BB * NN)        // 2097152
#define W1_ELEMS (NN * HH * NN)  // 262144

__device__ __forceinline__ unsigned short f32_to_bf16_bits(float f) {
    union { float f; unsigned int i; } c; c.f = f;
    unsigned int b = c.i;
    b += 0x7fffu + ((b >> 16) & 1u);   // RNE
    return (unsigned short)(b >> 16);
}

__device__ __forceinline__ bool sniff_bf16(const void* x) {
    // bf16 N(0,1): exponent field in [118,132] ~99%; fp32 low-mantissa halves ~6%.
    const int lane = threadIdx.x & 63;
    const ushort* xw = (const ushort*)x;
    const ushort a = xw[4 * lane];
    const ushort b = xw[4 * lane + 2];
    const int ea = (a >> 7) & 0xFF, eb = (b >> 7) & 0xFF;
    const int hit = ((ea >= 118 && ea <= 132) ? 1 : 0) + ((eb >= 118 && eb <= 132) ? 1 : 0);
    const unsigned long long m1 = __ballot(hit >= 1);
    const unsigned long long m2 = __ballot(hit >= 2);
    return (__popcll(m1) + __popcll(m2)) >= 64;
}

// ---------------- prep: gate+convert x, mask+convert W1 into bf16 workspace ----
__global__ __launch_bounds__(256, 4)
void prep_kernel(const void* __restrict__ x, const void* __restrict__ w1,
                 ushort* __restrict__ xo, ushort* __restrict__ w1o)
{
    const bool is_bf16 = sniff_bf16(x);
    const long base = ((long)blockIdx.x * 256 + (long)threadIdx.x) * 8;

    if (base < X_ELEMS) {
        const bool gate = (base & 63) < 16;   // uniform per 8-elem chunk
        short8 v;
        if (is_bf16) {
            v = *(const short8*)((const ushort*)x + base);
            if (gate) {
                #pragma unroll
                for (int j = 0; j < 8; ++j) {
                    const unsigned short u = (unsigned short)v[j];
                    const bool pos = ((u & 0x8000u) == 0) && ((u & 0x7fffu) != 0);
                    v[j] = pos ? (short)0x3F80 : (short)0;
                }
            }
        } else {
            const float* p = (const float*)x + base;
            const float4 f0 = *(const float4*)(p);
            const float4 f1 = *(const float4*)(p + 4);
            const float vals[8] = {f0.x, f0.y, f0.z, f0.w, f1.x, f1.y, f1.z, f1.w};
            #pragma unroll
            for (int j = 0; j < 8; ++j) {
                if (gate) v[j] = (vals[j] > 0.f) ? (short)0x3F80 : (short)0;
                else      v[j] = (short)f32_to_bf16_bits(vals[j]);
            }
        }
        *(short8*)(xo + base) = v;
    } else {
        const long wb = base - X_ELEMS;
        if (wb < W1_ELEMS) {
            short8 v;
            if (is_bf16) {
                v = *(const short8*)((const ushort*)w1 + wb);
            } else {
                const float* p = (const float*)w1 + wb;
                const float4 f0 = *(const float4*)(p);
                const float4 f1 = *(const float4*)(p + 4);
                const float vals[8] = {f0.x, f0.y, f0.z, f0.w, f1.x, f1.y, f1.z, f1.w};
                #pragma unroll
                for (int j = 0; j < 8; ++j) v[j] = (short)f32_to_bf16_bits(vals[j]);
            }
            const int node = (int)(wb >> 12);        // 4096 elems per node
            if (node == NN - 1) {                    // hidden node: keep only n==63
                const int w63 = (int)(wb & 63);
                #pragma unroll
                for (int j = 0; j < 8; ++j)
                    if (w63 + j != NN - 1) v[j] = 0;
            }
            *(short8*)(w1o + wb) = v;
        }
    }
}

// ---------------- main: fat waves — 16 nodes/wave, ping-pong W1 prefetch ------
template<bool F32>
__device__ __forceinline__ void main_body(const ushort* __restrict__ xo,
                                          const ushort* __restrict__ w1o,
                                          const void* __restrict__ w2p,
                                          void* __restrict__ outp,
                                          float* outTile)
{
    const int tid  = threadIdx.x;
    const int wave = tid >> 6;
    const int lane = tid & 63;
    const int quad = lane >> 4;   // 0..3
    const int l16  = lane & 15;   // 0..15

    const int blk = blockIdx.x;       // 0..511
    const int b0  = blk * 64;         // this block's 64 batch rows
    const int nbase = wave * 16;      // this wave's 16 nodes (global node ids)

    // ---- x fragments, loaded ONCE, reused by 16 node-GEMMs. Role: MFMA *B*
    //      B[k][bcol] = xo[b0+bcol][k]; bcol = nt*16+l16, k = ks*32+quad*8+j
    short8 xfrag[2][4];
    #pragma unroll
    for (int ks = 0; ks < 2; ++ks)
        #pragma unroll
        for (int nt = 0; nt < 4; ++nt)
            xfrag[ks][nt] = *(const short8*)(xo + (b0 + nt * 16 + l16) * NN + ks * 32 + quad * 8);

    // ---- W1 fragment loader (role: MFMA *A*): A[h][k] = W1[node][h][k]
    auto loadW1 = [&](short8 w[2][4], int node) {
        const ushort* w1n = w1o + node * (HH * NN);
        #pragma unroll
        for (int ks = 0; ks < 2; ++ks)
            #pragma unroll
            for (int mt = 0; mt < 4; ++mt)
                w[ks][mt] = *(const short8*)(w1n + (mt * 16 + l16) * NN + ks * 32 + quad * 8);
    };

    // ---- one node's GEMM + in-lane epilogue (r11-proven layout)
    auto computeNode = [&](const short8 w[2][4], int node) {
        // W2 loads issued first; needed only after the 32 MFMAs -> latency hidden
        float w2v[4][4];
        #pragma unroll
        for (int mt = 0; mt < 4; ++mt) {
            const int idx = node * HH + mt * 16 + quad * 4;
            if (F32) {
                const float4 ww = *(const float4*)((const float*)w2p + idx);
                w2v[mt][0] = ww.x; w2v[mt][1] = ww.y; w2v[mt][2] = ww.z; w2v[mt][3] = ww.w;
            } else {
                const ushort4 ww = *(const ushort4*)((const ushort*)w2p + idx);
                union { unsigned int i; float f; } c0, c1, c2, c3;
                c0.i = ((unsigned int)ww.x) << 16; c1.i = ((unsigned int)ww.y) << 16;
                c2.i = ((unsigned int)ww.z) << 16; c3.i = ((unsigned int)ww.w) << 16;
                w2v[mt][0] = c0.f; w2v[mt][1] = c1.f; w2v[mt][2] = c2.f; w2v[mt][3] = c3.f;
            }
        }

        // MFMA (transposed): acc[mt][nt] = Hid^T tile; D row = h offset
        // (quad*4+r within mt), D col = batch (l16 within nt).
        floatx4 acc[4][4];
        #pragma unroll
        for (int mt = 0; mt < 4; ++mt)
            #pragma unroll
            for (int nt = 0; nt < 4; ++nt)
                acc[mt][nt] = (floatx4){0.f, 0.f, 0.f, 0.f};

        #pragma unroll
        for (int ks = 0; ks < 2; ++ks)
            #pragma unroll
            for (int mt = 0; mt < 4; ++mt)
                #pragma unroll
                for (int nt = 0; nt < 4; ++nt)
                    acc[mt][nt] = __builtin_amdgcn_mfma_f32_16x16x32_bf16(
                        w[ks][mt], xfrag[ks][nt], acc[mt][nt], 0, 0, 0);

        // in-lane: psum[nt] = sum over this lane's 16 h-values
        float psum[4];
        #pragma unroll
        for (int nt = 0; nt < 4; ++nt) {
            float s0 = 0.f, s1 = 0.f;
            #pragma unroll
            for (int mt = 0; mt < 4; ++mt) {
                float a0 = acc[mt][nt][0]; a0 = a0 > 0.f ? a0 : 0.f;
                float a1 = acc[mt][nt][1]; a1 = a1 > 0.f ? a1 : 0.f;
                float a2 = acc[mt][nt][2]; a2 = a2 > 0.f ? a2 : 0.f;
                float a3 = acc[mt][nt][3]; a3 = a3 > 0.f ? a3 : 0.f;
                s0 = fmaf(a0, w2v[mt][0], s0); s1 = fmaf(a1, w2v[mt][1], s1);
                s0 = fmaf(a2, w2v[mt][2], s0); s1 = fmaf(a3, w2v[mt][3], s1);
            }
            psum[nt] = s0 + s1;
        }

        // reduce across the 4 quads (same batch col, different h ranges)
        #pragma unroll
        for (int nt = 0; nt < 4; ++nt) {
            psum[nt] += __shfl_xor(psum[nt], 16, 64);
            psum[nt] += __shfl_xor(psum[nt], 32, 64);
        }

        // lane's batch row == lane (nt = quad, col = l16): select psum[quad]
        const float val = (quad == 0) ? psum[0] : (quad == 1) ? psum[1]
                         : (quad == 2) ? psum[2] : psum[3];
        outTile[lane * OTW + node] = val;   // lane-major: 2-way aliasing only
    };

    // ---- 16-node loop, ping-pong double buffer (no register rotation)
    short8 wA[2][4], wB[2][4];
    loadW1(wA, nbase);
    #pragma unroll 1
    for (int np = 0; np < 16; np += 2) {
        loadW1(wB, nbase + np + 1);          // np+1 <= 15 always
        computeNode(wA, nbase + np);
        if (np + 2 < 16) loadW1(wA, nbase + np + 2);
        computeNode(wB, nbase + np + 1);
    }

    __syncthreads();   // all 64 out-tile columns written

    // ---- output: thread -> (row = tid>>2, quarter q = tid&3); each thread
    // writes 64B contiguous (one full cache line): out[b0+row][q*16 .. q*16+15]
    const int row = tid >> 2;
    const int q   = tid & 3;
    const float* rp = outTile + row * OTW + q * 16;
    const size_t obase = (size_t)(b0 + row) * NN + q * 16;
    if (F32) {
        float* op = (float*)outp + obase;
        #pragma unroll
        for (int c = 0; c < 4; ++c) {
            const float4 v = make_float4(rp[c*4+0], rp[c*4+1], rp[c*4+2], rp[c*4+3]);
            *(float4*)(op + c * 4) = v;
        }
    } else {
        ushort* op = (ushort*)outp + obase;
        #pragma unroll
        for (int c = 0; c < 4; ++c) {
            ushort4 o;
            o.x = f32_to_bf16_bits(rp[c*4+0]); o.y = f32_to_bf16_bits(rp[c*4+1]);
            o.z = f32_to_bf16_bits(rp[c*4+2]); o.w = f32_to_bf16_bits(rp[c*4+3]);
            *(ushort4*)(op + c * 4) = o;
        }
    }
}

__global__ __launch_bounds__(256, 2)
void main_kernel(const void* __restrict__ xorig,
                 const ushort* __restrict__ xo, const ushort* __restrict__ w1o,
                 const void* __restrict__ w2p, void* __restrict__ outp)
{
    __shared__ float outTile[64 * OTW];   // 16.6 KB
    const bool is_bf16 = sniff_bf16(xorig);
    if (is_bf16) main_body<false>(xo, w1o, w2p, outp, outTile);
    else         main_body<true >(xo, w1o, w2p, outp, outTile);
}

// ---------------- fallback: round-6 proven single kernel ----------------------
#define LDSW 20
template<bool F32>
__device__ __forceinline__ void run_body_fb(const void* xp, const void* w1p,
                                            const void* w2p, void* outp,
                                            float* myLds)
{
    const int tid  = threadIdx.x;
    const int wave = tid >> 6;
    const int lane = tid & 63;
    const int quad = lane >> 4;
    const int l16  = lane & 15;
    const int blk  = blockIdx.x;
    const int ng   = blk >> 7;
    const int rbg  = blk & 127;
    const int node = ng * 4 + wave;
    const int rowbase = rbg * 256;

    short8 bfrag[2][4];
    #pragma unroll
    for (int ks = 0; ks < 2; ++ks) {
        #pragma unroll
        for (int ht = 0; ht < 4; ++ht) {
            const int h = ht * 16 + l16;
            const int k = ks * 32 + quad * 8;
            short8 v;
            if (F32) {
                const float* p = (const float*)w1p + node * (HH * NN) + h * NN + k;
                const float4 a0 = *(const float4*)(p);
                const float4 a1 = *(const float4*)(p + 4);
                const float vals[8] = {a0.x, a0.y, a0.z, a0.w, a1.x, a1.y, a1.z, a1.w};
                #pragma unroll
                for (int j = 0; j < 8; ++j) v[j] = (short)f32_to_bf16_bits(vals[j]);
            } else {
                v = *(const short8*)((const ushort*)w1p + node * (HH * NN) + h * NN + k);
            }
            if (node == NN - 1) {
                #pragma unroll
                for (int j = 0; j < 8; ++j)
                    if (k + j != NN - 1) v[j] = 0;
            }
            bfrag[ks][ht] = v;
        }
    }

    float w2reg[4];
    #pragma unroll
    for (int ht = 0; ht < 4; ++ht) {
        const int idx = node * HH + ht * 16 + l16;
        if (F32) {
            w2reg[ht] = ((const float*)w2p)[idx];
        } else {
            const ushort u = ((const ushort*)w2p)[idx];
            union { unsigned int i; float f; } cv; cv.i = ((unsigned int)u) << 16;
            w2reg[ht] = cv.f;
        }
    }

    #pragma unroll 1
    for (int it = 0; it < 4; ++it) {
        const int b0 = rowbase + it * 64;
        short8 afrag[2][4];
        #pragma unroll
        for (int ks = 0; ks < 2; ++ks) {
            #pragma unroll
            for (int rt = 0; rt < 4; ++rt) {
                const int rowg = b0 + rt * 16 + l16;
                const int k    = ks * 32 + quad * 8;
                const bool gate = (ks == 0 && quad < 2);
                short8 v;
                if (F32) {
                    const float* p = (const float*)xp + rowg * NN + k;
                    const float4 a0 = *(const float4*)(p);
                    const float4 a1 = *(const float4*)(p + 4);
                    const float vals[8] = {a0.x, a0.y, a0.z, a0.w, a1.x, a1.y, a1.z, a1.w};
                    #pragma unroll
                    for (int j = 0; j < 8; ++j) {
                        if (gate) v[j] = (vals[j] > 0.f) ? (short)0x3F80 : (short)0;
                        else      v[j] = (short)f32_to_bf16_bits(vals[j]);
                    }
                } else {
                    v = *(const short8*)((const ushort*)xp + rowg * NN + k);
                    if (gate) {
                        #pragma unroll
                        for (int j = 0; j < 8; ++j) {
                            const unsigned short u = (unsigned short)v[j];
                            const bool pos = ((u & 0x8000u) == 0) && ((u & 0x7fffu) != 0);
                            v[j] = pos ? (short)0x3F80 : (short)0;
                        }
                    }
                }
                afrag[ks][rt] = v;
            }
        }

        floatx4 acc[4][4];
        #pragma unroll
        for (int rt = 0; rt < 4; ++rt)
            #pragma unroll
            for (int ht = 0; ht < 4; ++ht)
                acc[rt][ht] = (floatx4){0.f, 0.f, 0.f, 0.f};
        #pragma unroll
        for (int ks = 0; ks < 2; ++ks)
            #pragma unroll
            for (int rt = 0; rt < 4; ++rt)
                #pragma unroll
                for (int ht = 0; ht < 4; ++ht)
                    acc[rt][ht] = __builtin_amdgcn_mfma_f32_16x16x32_bf16(
                        afrag[ks][rt], bfrag[ks][ht], acc[rt][ht], 0, 0, 0);

        #pragma unroll
        for (int rt = 0; rt < 4; ++rt) {
            #pragma unroll
            for (int r = 0; r < 4; ++r) {
                float s = 0.f;
                #pragma unroll
                for (int ht = 0; ht < 4; ++ht) {
                    float v = acc[rt][ht][r];
                    v = v > 0.f ? v : 0.f;
                    s = fmaf(v, w2reg[ht], s);
                }
                myLds[(rt * 16 + quad * 4 + r) * LDSW + l16] = s;
            }
        }
        __syncthreads();
        const float* rowp = myLds + lane * LDSW;
        const float4 v0 = *(const float4*)(rowp + 0);
        const float4 v1 = *(const float4*)(rowp + 4);
        const float4 v2 = *(const float4*)(rowp + 8);
        const float4 v3 = *(const float4*)(rowp + 12);
        const float tot = (((v0.x + v0.y) + (v0.z + v0.w)) + ((v1.x + v1.y) + (v1.z + v1.w)))
                        + (((v2.x + v2.y) + (v2.z + v2.w)) + ((v3.x + v3.y) + (v3.z + v3.w)));
        if (F32) ((float*) outp)[(size_t)(b0 + lane) * NN + node] = tot;
        else     ((ushort*)outp)[(size_t)(b0 + lane) * NN + node] = f32_to_bf16_bits(tot);
        __syncthreads();
    }
}

__global__ __launch_bounds__(256, 2)
void fallback_kernel(const void* __restrict__ x, const void* __restrict__ W1,
                     const void* __restrict__ W2, void* __restrict__ out)
{
    __shared__ float lds[4][64 * LDSW];
    const bool is_bf16 = sniff_bf16(x);
    float* myLds = &lds[threadIdx.x >> 6][0];
    if (is_bf16) run_body_fb<false>(x, W1, W2, out, myLds);
    else         run_body_fb<true >(x, W1, W2, out, myLds);
}

extern "C" void kernel_launch(void* const* d_in, const int* in_sizes, int n_in,
                              void* d_out, int out_size, void* d_ws, size_t ws_size,
                              hipStream_t stream) {
    // Resolve inputs by element count (robust to the scalar t being dropped):
    //   inputs = 2097152, W1 = 262144, W2 = first 4096 (adjacency is the other 4096).
    int i_in = -1, i_w1 = -1, i_w2 = -1;
    for (int i = 0; i < n_in; ++i) {
        const int s = in_sizes[i];
        if      (s == BB * NN  && i_in < 0) i_in = i;
        else if (s == NN*HH*NN && i_w1 < 0) i_w1 = i;
        else if (s == NN*HH    && i_w2 < 0) i_w2 = i;
    }
    if (i_in < 0) i_in = (n_in > 1) ? 1 : 0;
    if (i_w1 < 0) i_w1 = i_in + 1;
    if (i_w2 < 0) i_w2 = i_w1 + 1;

    const size_t need = (size_t)(X_ELEMS + W1_ELEMS) * sizeof(ushort);  // 4.5 MiB
    if (ws_size >= need) {
        ushort* xo  = (ushort*)d_ws;
        ushort* w1o = xo + X_ELEMS;
        prep_kernel<<<dim3((X_ELEMS + W1_ELEMS) / (256 * 8)), dim3(256), 0, stream>>>(
            d_in[i_in], d_in[i_w1], xo, w1o);
        main_kernel<<<dim3(512), dim3(256), 0, stream>>>(
            d_in[i_in], xo, w1o, d_in[i_w2], d_out);
    } else {
        fallback_kernel<<<dim3(16 * 128), dim3(256), 0, stream>>>(
            d_in[i_in], d_in[i_w1], d_in[i_w2], d_out);
    }
}